// Round 12
// baseline (941.799 us; speedup 1.0000x reference)
//
#include <hip/hip_runtime.h>
#include <cstdint>
#include <cstddef>

#define D_DIM 256
#define T_DIM 512
#define B_DIM 128
#define S_DIM 512

typedef __attribute__((ext_vector_type(8))) short short8;
typedef __attribute__((ext_vector_type(4))) float f32x4;

// ---------- helpers ----------
__device__ inline unsigned short f2bf(float x) {
    unsigned u = __builtin_bit_cast(unsigned, x);
    unsigned r = (u + 0x7fffu + ((u >> 16) & 1u)) >> 16;
    return (unsigned short)r;
}
__device__ inline float bf2f(unsigned short b) {
    unsigned u = ((unsigned)b) << 16;
    return __builtin_bit_cast(float, u);
}
__device__ inline float fast_tanh(float x) {
    float ax = __builtin_fabsf(x);
    float e  = __expf(-2.0f * ax);
    float r  = (1.0f - e) * __builtin_amdgcn_rcpf(1.0f + e);
    return __builtin_copysignf(r, x);
}

// Truncation split: x = bf2f(hi) + lo-term; residual exact, lo truncated ->
// total err <= 2^-16 |x|.  Pair-packed: low 16 bits of .x = element 0.
__device__ inline void split4(float4 v, uint2& hi, uint2& lo) {
    unsigned u0 = __builtin_bit_cast(unsigned, v.x);
    unsigned u1 = __builtin_bit_cast(unsigned, v.y);
    unsigned u2 = __builtin_bit_cast(unsigned, v.z);
    unsigned u3 = __builtin_bit_cast(unsigned, v.w);
    hi.x = (u0 >> 16) | (u1 & 0xFFFF0000u);
    hi.y = (u2 >> 16) | (u3 & 0xFFFF0000u);
    float r0 = v.x - __builtin_bit_cast(float, u0 & 0xFFFF0000u);
    float r1 = v.y - __builtin_bit_cast(float, u1 & 0xFFFF0000u);
    float r2 = v.z - __builtin_bit_cast(float, u2 & 0xFFFF0000u);
    float r3 = v.w - __builtin_bit_cast(float, u3 & 0xFFFF0000u);
    lo.x = (__builtin_bit_cast(unsigned, r0) >> 16)
         | (__builtin_bit_cast(unsigned, r1) & 0xFFFF0000u);
    lo.y = (__builtin_bit_cast(unsigned, r2) >> 16)
         | (__builtin_bit_cast(unsigned, r3) & 0xFFFF0000u);
}

// ---------- split-bf16 MFMA GEMM v4 (R11-verified): BK=32, 3 blocks/CU -----
__global__ __launch_bounds__(256, 3)
void gemm_bt_mfma(const float* __restrict__ A, const float* __restrict__ Bm,
                  float* __restrict__ C,
                  const float* __restrict__ bias1, const float* __restrict__ bias2,
                  const int* __restrict__ ids, const float* __restrict__ emb,
                  int M, int N, int K)
{
    // planes (bf16 [128 rows][32 k], row = 64B): Ahi@0 Alo@8K Bhi@16K Blo@24K
    __shared__ char smem[32768];

    const int tid  = threadIdx.x;
    const int lane = tid & 63;
    const int quad = lane >> 4;
    const int lcol = lane & 15;
    const int wv   = tid >> 6;
    const int wm   = (wv & 1) * 64;
    const int wn   = (wv >> 1) * 64;
    const int m0   = blockIdx.x * 128;
    const int n0   = blockIdx.y * 128;

    // staging map: thread t -> row rs = t>>1, k-half hf = t&1
    const int rs = tid >> 1;
    const int hf = tid & 1;
    const int gmA = m0 + rs;
    const float* arow = (ids ? (emb + (size_t)ids[gmA] * K)
                             : (A + (size_t)gmA * K)) + hf * 16;
    const float* brow = Bm + (size_t)(n0 + rs) * K + hf * 16;

    // swizzled 16B-slot write offsets
    const int swz = ((rs >> 1) & 3) << 4;
    const int ws0 = rs * 64 + (((hf * 2)     << 4) ^ swz);
    const int ws1 = rs * 64 + (((hf * 2 + 1) << 4) ^ swz);

    f32x4 acc[4][4];
#pragma unroll
    for (int mt = 0; mt < 4; ++mt)
#pragma unroll
        for (int nt = 0; nt < 4; ++nt) acc[mt][nt] = (f32x4){0.f, 0.f, 0.f, 0.f};

    // prologue: prefetch A for iter 0
    float4 pa0 = *(const float4*)(arow + 0);
    float4 pa1 = *(const float4*)(arow + 4);
    float4 pa2 = *(const float4*)(arow + 8);
    float4 pa3 = *(const float4*)(arow + 12);

    for (int it = 0; it < 8; ++it) {
        const int kc = it * 32;
        float4 pb0 = *(const float4*)(brow + kc + 0);
        float4 pb1 = *(const float4*)(brow + kc + 4);
        float4 pb2 = *(const float4*)(brow + kc + 8);
        float4 pb3 = *(const float4*)(brow + kc + 12);

        if (it) __syncthreads();

        {   // A planes
            uint2 h0, l0, h1, l1, h2, l2, h3, l3;
            split4(pa0, h0, l0); split4(pa1, h1, l1);
            split4(pa2, h2, l2); split4(pa3, h3, l3);
            *(uint4*)(smem + 0    + ws0) = make_uint4(h0.x, h0.y, h1.x, h1.y);
            *(uint4*)(smem + 0    + ws1) = make_uint4(h2.x, h2.y, h3.x, h3.y);
            *(uint4*)(smem + 8192 + ws0) = make_uint4(l0.x, l0.y, l1.x, l1.y);
            *(uint4*)(smem + 8192 + ws1) = make_uint4(l2.x, l2.y, l3.x, l3.y);
        }
        {   // B planes
            uint2 h0, l0, h1, l1, h2, l2, h3, l3;
            split4(pb0, h0, l0); split4(pb1, h1, l1);
            split4(pb2, h2, l2); split4(pb3, h3, l3);
            *(uint4*)(smem + 16384 + ws0) = make_uint4(h0.x, h0.y, h1.x, h1.y);
            *(uint4*)(smem + 16384 + ws1) = make_uint4(h2.x, h2.y, h3.x, h3.y);
            *(uint4*)(smem + 24576 + ws0) = make_uint4(l0.x, l0.y, l1.x, l1.y);
            *(uint4*)(smem + 24576 + ws1) = make_uint4(l2.x, l2.y, l3.x, l3.y);
        }
        __syncthreads();

        if (it < 7) {
            pa0 = *(const float4*)(arow + kc + 32);
            pa1 = *(const float4*)(arow + kc + 36);
            pa2 = *(const float4*)(arow + kc + 40);
            pa3 = *(const float4*)(arow + kc + 44);
        }

        short8 aHi[4], aLo[4], bHi[4], bLo[4];
#pragma unroll
        for (int mt = 0; mt < 4; ++mt) {
            int m = wm + mt * 16 + lcol;
            int off = m * 64 + ((quad * 16) ^ ((((m >> 1) & 3)) << 4));
            aHi[mt] = *(const short8*)(smem + off);
            aLo[mt] = *(const short8*)(smem + 8192 + off);
        }
#pragma unroll
        for (int nt = 0; nt < 4; ++nt) {
            int n = wn + nt * 16 + lcol;
            int off = n * 64 + ((quad * 16) ^ ((((n >> 1) & 3)) << 4));
            bHi[nt] = *(const short8*)(smem + 16384 + off);
            bLo[nt] = *(const short8*)(smem + 24576 + off);
        }
#pragma unroll
        for (int mt = 0; mt < 4; ++mt)
#pragma unroll
            for (int nt = 0; nt < 4; ++nt) {
                acc[mt][nt] = __builtin_amdgcn_mfma_f32_16x16x32_bf16(aHi[mt], bHi[nt], acc[mt][nt], 0, 0, 0);
                acc[mt][nt] = __builtin_amdgcn_mfma_f32_16x16x32_bf16(aLo[mt], bHi[nt], acc[mt][nt], 0, 0, 0);
                acc[mt][nt] = __builtin_amdgcn_mfma_f32_16x16x32_bf16(aHi[mt], bLo[nt], acc[mt][nt], 0, 0, 0);
            }
    }

    float bv[4];
#pragma unroll
    for (int nt = 0; nt < 4; ++nt) {
        int gn = n0 + wn + nt * 16 + lcol;
        float v = 0.f;
        if (bias1) v += bias1[gn];
        if (bias2) v += bias2[gn];
        bv[nt] = v;
    }
#pragma unroll
    for (int mt = 0; mt < 4; ++mt) {
        int gmb = m0 + wm + mt * 16 + quad * 4;
#pragma unroll
        for (int r = 0; r < 4; ++r) {
            float* crow = C + (size_t)(gmb + r) * N + n0 + wn;
#pragma unroll
            for (int nt = 0; nt < 4; ++nt)
                crow[nt * 16 + lcol] = acc[mt][nt][r] + bv[nt];
        }
    }
}

// LDS-only barrier (R1: neutral vs __syncthreads; kept, documents intent).
__device__ inline void lds_barrier() {
    asm volatile("s_waitcnt lgkmcnt(0)" ::: "memory");
    __builtin_amdgcn_s_barrier();
    __builtin_amdgcn_sched_barrier(0);
}

// ---------- MFMA Elman scan v4: 16 waves x 16 units, hh+lh ----------
// R11 post-mortem: chain-split was neutral (-5us) -- at 2 waves/SIMD the
// issue pipe was saturated; the ~750-cyc serial residual (ds_read -> dep
// MFMA chain -> tanh -> pack -> barrier) lacked WAVES to hide it.  v4:
// 16 waves x 16 units (1024 thr), 8 MFMA/wave/step, 4 waves/SIMD -- same
// 128 MFMA/CU/step issue floor, 2x the TLP to overlap serial sections.
// Arithmetic per unit is identical (hh+lh, same kt order) -> same absmax.
__global__ __launch_bounds__(1024) __attribute__((amdgpu_waves_per_eu(4, 4)))
void rnn_scan_mfma(const float* __restrict__ pre, const float* __restrict__ Whh,
                   float* __restrict__ hout)
{
    const int tid  = threadIdx.x;
    const int wave = tid >> 6;
    const int lane = tid & 63;
    const int quad = lane >> 4;
    const int lcol = lane & 15;
    const int b    = blockIdx.x;

    // LDS layout (shorts): Hh[0]@0, Hl[0]@256, Hh[1]@512, Hl[1]@768.
    __shared__ short lds[1024];
    lds[tid] = 0;

    // --- W_hh hi fragments: 1 tile of 16 units per wave ---
    short8 wh[8];
    {
        const int n = wave * 16 + lcol;
        const float* wr = Whh + (size_t)n * D_DIM + quad * 8;
#pragma unroll
        for (int kt = 0; kt < 8; ++kt) {
            float4 x0 = *(const float4*)(wr + kt * 32);
            float4 x1 = *(const float4*)(wr + kt * 32 + 4);
            float xs[8] = {x0.x, x0.y, x0.z, x0.w, x1.x, x1.y, x1.z, x1.w};
            short8 hi8;
#pragma unroll
            for (int j = 0; j < 8; ++j) hi8[j] = (short)f2bf(xs[j]);
            wh[kt] = hi8;
        }
    }

    const bool active = (lane < 16);           // quad==0 holds C rows 0..3
    const int n0 = wave * 16 + lcol;           // this wave's unit
    const size_t rowbase = (size_t)b * T_DIM * D_DIM;

    // Persistent packed A fragment: row 0 (lcol==0) = h_hi, row 1 (lcol==1)
    // = h_lo, rows 2..15 permanently zero.
    const short8 ZS = {0, 0, 0, 0, 0, 0, 0, 0};
    short8 aP[8];
#pragma unroll
    for (int kt = 0; kt < 8; ++kt) aP[kt] = ZS;

    const int aq = quad * 8;                   // k-chunk within buffer

    // 2-step-deep pre pipeline
    float pv0 = 0.f, nv0 = 0.f;
    if (active) {
        pv0 = pre[rowbase + n0];
        nv0 = pre[rowbase + D_DIM + n0];
    }
    lds_barrier();

    const f32x4 Z = {0.f, 0.f, 0.f, 0.f};

    for (int t = 0; t < T_DIM; ++t) {
        // prefetch step t+2's pre
        float qv0 = 0.f;
        if (active && t + 2 < T_DIM)
            qv0 = pre[rowbase + (size_t)(t + 2) * D_DIM + n0];

        // exec-masked A loads: lcol==0 reads h_hi, lcol==1 reads h_lo
        const int bh = (t & 1) ? 512 : 0;
        if (lcol < 2) {
            const short* pa = lds + bh + lcol * 256 + aq;
#pragma unroll
            for (int kt = 0; kt < 8; ++kt)
                aP[kt] = *(const short8*)(pa + kt * 32);
        }

        // single 8-deep chain: C row0 = hh, row1 = lh (free)
        f32x4 c;
        c = __builtin_amdgcn_mfma_f32_16x16x32_bf16(aP[0], wh[0], Z, 0, 0, 0);
#pragma unroll
        for (int kt = 1; kt < 8; ++kt)
            c = __builtin_amdgcn_mfma_f32_16x16x32_bf16(aP[kt], wh[kt], c, 0, 0, 0);

        // epilogue: lanes 0..15 hold C rows 0 (reg 0: hh) and 1 (reg 1: lh)
        if (active) {
            const int wH = (t & 1) ? 0 : 512;   // write the other buffer
            float x0 = c[0] + c[1] + pv0;
            float h0 = fast_tanh(x0);
            unsigned short h0h = f2bf(h0);
            unsigned short h0l = f2bf(h0 - bf2f(h0h));
            lds[wH + n0]       = (short)h0h;
            lds[wH + 256 + n0] = (short)h0l;
            hout[rowbase + (size_t)t * D_DIM + n0] = h0;   // stays in flight
        }
        pv0 = nv0;
        nv0 = qv0;
        lds_barrier();
    }
}

extern "C" void kernel_launch(void* const* d_in, const int* in_sizes, int n_in,
                              void* d_out, int out_size, void* d_ws, size_t ws_size,
                              hipStream_t stream)
{
    const int*   ids    = (const int*)  d_in[0];
    const float* emb    = (const float*)d_in[1];
    const float* W_ih0  = (const float*)d_in[2];
    const float* W_hh0  = (const float*)d_in[3];
    const float* b_ih0  = (const float*)d_in[4];
    const float* b_hh0  = (const float*)d_in[5];
    const float* W_ih1  = (const float*)d_in[6];
    const float* W_hh1  = (const float*)d_in[7];
    const float* b_ih1  = (const float*)d_in[8];
    const float* b_hh1  = (const float*)d_in[9];
    const float* W_head = (const float*)d_in[10];

    float* out = (float*)d_out;
    const int M = B_DIM * T_DIM;              // 65536
    float* pre0 = out;                        // d_out doubles as scratch
    float* pre1 = out + (size_t)M * D_DIM;
    float* h1   = (float*)d_ws;               // 64 MB of ws
    float* h2   = h1;

    // pre0 = emb[ids] @ W_ih0^T + (b_ih0 + b_hh0)
    gemm_bt_mfma<<<dim3(M / 128, D_DIM / 128), dim3(256), 0, stream>>>(
        nullptr, W_ih0, pre0, b_ih0, b_hh0, ids, emb, M, D_DIM, D_DIM);
    // layer-0 recurrence (16 waves x 16 units)
    rnn_scan_mfma<<<dim3(B_DIM), dim3(1024), 0, stream>>>(pre0, W_hh0, h1);
    // pre1 = h1 @ W_ih1^T + (b_ih1 + b_hh1)
    gemm_bt_mfma<<<dim3(M / 128, D_DIM / 128), dim3(256), 0, stream>>>(
        h1, W_ih1, pre1, b_ih1, b_hh1, nullptr, nullptr, M, D_DIM, D_DIM);
    // layer-1 recurrence
    rnn_scan_mfma<<<dim3(B_DIM), dim3(1024), 0, stream>>>(pre1, W_hh1, h2);
    // logits = h2 @ W_head^T
    gemm_bt_mfma<<<dim3(M / 128, S_DIM / 128), dim3(256), 0, stream>>>(
        h2, W_head, out, nullptr, nullptr, nullptr, nullptr, M, S_DIM, D_DIM);
}